// Round 4
// baseline (1980.819 us; speedup 1.0000x reference)
//
#include <hip/hip_runtime.h>

#define NN 100000
#define NE 3200000
#define DD 128
#define KC 10
#define NITER 10
#define NBK 512
#define NTHR 256
#define NPAIR (NN / 2)

#define AG __HIP_MEMORY_SCOPE_AGENT

static __device__ __forceinline__ float agload(const float* p) {
  return __hip_atomic_load(p, __ATOMIC_RELAXED, AG);
}
static __device__ __forceinline__ void agstore(float* p, float v) {
  __hip_atomic_store(p, v, __ATOMIC_RELAXED, AG);
}

template <int CTRL, int RM>
__device__ __forceinline__ float dppadd(float v) {
  int t = __builtin_amdgcn_update_dpp(0, __builtin_bit_cast(int, v), CTRL, RM,
                                      0xF, true);
  return v + __builtin_bit_cast(float, t);
}

// After this: lane 31 holds sum of lanes 0..31, lane 63 holds sum of 32..63.
__device__ __forceinline__ float halfsum_tail(float v) {
  v = dppadd<0x111, 0xF>(v);  // row_shr:1
  v = dppadd<0x112, 0xF>(v);  // row_shr:2
  v = dppadd<0x114, 0xF>(v);  // row_shr:4
  v = dppadd<0x118, 0xF>(v);  // row_shr:8
  v = dppadd<0x142, 0xA>(v);  // row_bcast:15 into rows 1,3
  return v;
}
// broadcast lane 31 -> lanes 0..31 and lane 63 -> lanes 32..63
__device__ __forceinline__ float bcast31f(float v) {
  return __builtin_bit_cast(
      float, __builtin_amdgcn_ds_swizzle(__builtin_bit_cast(int, v), 0x3E0));
}
__device__ __forceinline__ int bcast31i(int v) {
  return __builtin_amdgcn_ds_swizzle(v, 0x3E0);
}

// manual grid barrier: all NBK blocks co-resident by construction
__device__ __forceinline__ void gsync(int* bar, int target) {
  __syncthreads();
  if (threadIdx.x == 0) {
    __hip_atomic_fetch_add(bar, 1, __ATOMIC_ACQ_REL, AG);
    while (__hip_atomic_load(bar, __ATOMIC_ACQUIRE, AG) < target)
      __builtin_amdgcn_s_sleep(1);
  }
  __syncthreads();
}

__global__ __launch_bounds__(NTHR, 2) void k_coop(
    const float* __restrict__ x, const float* __restrict__ WQ,
    const float* __restrict__ WV, float* __restrict__ sums,
    float* __restrict__ denomf, float* __restrict__ partial,
    float* __restrict__ cntpart, unsigned char* __restrict__ cl8,
    float* __restrict__ CA, int* __restrict__ bar) {
  __shared__ float cs[KC][DD];
  __shared__ float wsum[4][KC][DD];
  __shared__ float wcnt[4][KC];
  __shared__ float q[KC][DD], vv[KC][DD], pr[KC][KC];
  const int tid = threadIdx.x;
  const int w = tid >> 6, lane = tid & 63, half = lane >> 5, hl = lane & 31;
  const float4* __restrict__ x4 = (const float4*)x;
  int gen = 0;

  for (int it = 0; it < NITER; ++it) {
    // ---- materialize centroids ----
    if (it == 0) {
      for (int i = tid; i < KC * DD; i += NTHR) ((float*)cs)[i] = x[i];
    } else {
      for (int i = tid; i < KC * DD; i += NTHR)
        ((float*)cs)[i] = agload(&sums[i]) / agload(&denomf[i >> 7]);
    }
    __syncthreads();

    // per-lane centroid fragment + bias = -0.5*|c_frag|^2
    float4 cfrag[KC];
    float bias[KC];
#pragma unroll
    for (int j = 0; j < KC; ++j) {
      const float4 c4 = *(const float4*)&cs[j][hl * 4];
      cfrag[j] = c4;
      bias[j] = -0.5f * (c4.x * c4.x + c4.y * c4.y + c4.z * c4.z + c4.w * c4.w);
    }

    float4 acc[KC];
    float cntacc[KC];
#pragma unroll
    for (int j = 0; j < KC; ++j) {
      acc[j] = float4{0.f, 0.f, 0.f, 0.f};
      cntacc[j] = 0.f;
    }

    const int last = (it == NITER - 1);
    // half-wave per row; score = dot(x,c) - 0.5|c|^2; argmax == argmin dist
    for (int p = blockIdx.x * 4 + w; p < NPAIR; p += NBK * 4) {
      const int row = 2 * p + half;
      const float4 v = x4[(size_t)row * (DD / 4) + hl];
      float d[KC];
#pragma unroll
      for (int j = 0; j < KC; ++j)
        d[j] = bias[j] + v.x * cfrag[j].x + v.y * cfrag[j].y +
               v.z * cfrag[j].z + v.w * cfrag[j].w;
#pragma unroll
      for (int j = 0; j < KC; ++j) d[j] = halfsum_tail(d[j]);
      int best = 0;  // meaningful in lanes 31/63 only
      float bd = d[0];
#pragma unroll
      for (int j = 1; j < KC; ++j) {
        if (d[j] > bd) { bd = d[j]; best = j; }
      }
      best = bcast31i(best);
      const float g = (hl == 0) ? 1.f : 0.f;
#pragma unroll
      for (int j = 0; j < KC; ++j) {
        const float f = (best == j) ? 1.f : 0.f;
        acc[j].x += f * v.x;
        acc[j].y += f * v.y;
        acc[j].z += f * v.z;
        acc[j].w += f * v.w;
        cntacc[j] += (best == j) ? g : 0.f;
      }
      if (last && hl == 0) cl8[row] = (unsigned char)best;
    }
    // combine the two halves (lane ^ 32), flush half 0 into LDS
#pragma unroll
    for (int j = 0; j < KC; ++j) {
      acc[j].x += __shfl_xor(acc[j].x, 32);
      acc[j].y += __shfl_xor(acc[j].y, 32);
      acc[j].z += __shfl_xor(acc[j].z, 32);
      acc[j].w += __shfl_xor(acc[j].w, 32);
      cntacc[j] += __shfl_xor(cntacc[j], 32);
    }
    if (half == 0) {
#pragma unroll
      for (int j = 0; j < KC; ++j) *(float4*)&wsum[w][j][hl * 4] = acc[j];
      if (hl == 0) {
#pragma unroll
        for (int j = 0; j < KC; ++j) wcnt[w][j] = cntacc[j];
      }
    }
    __syncthreads();
    const float* wsf = (const float*)wsum;
    for (int i = tid; i < KC * DD; i += NTHR)
      agstore(&partial[(size_t)blockIdx.x * (KC * DD) + i],
              wsf[i] + wsf[KC * DD + i] + wsf[2 * KC * DD + i] +
                  wsf[3 * KC * DD + i]);
    if (tid < KC)
      agstore(&cntpart[blockIdx.x * KC + tid],
              wcnt[0][tid] + wcnt[1][tid] + wcnt[2][tid] + wcnt[3][tid]);
    gsync(bar, (++gen) * NBK);

    // ---- phase B: reduce partials (one wave per output column) ----
    const int W = blockIdx.x * 4 + w;
    if (W < KC * DD) {
      const int j = W >> 7, k = W & (DD - 1);
      float s = 0.f;
#pragma unroll
      for (int b = lane; b < NBK; b += 64)
        s += agload(&partial[(size_t)b * (KC * DD) + j * DD + k]);
      s = bcast31f(halfsum_tail(s));
      s += __shfl_xor(s, 32);
      if (lane == 0) agstore(&sums[j * DD + k], s);
    } else if (W < KC * DD + KC) {
      const int j = W - KC * DD;
      float s = 0.f;
#pragma unroll
      for (int b = lane; b < NBK; b += 64) s += agload(&cntpart[b * KC + j]);
      s = bcast31f(halfsum_tail(s));
      s += __shfl_xor(s, 32);
      if (lane == 0) agstore(&denomf[j], fmaxf(s, 1.f));
    }
    gsync(bar, (++gen) * NBK);
  }

  // ---- centroid attention (block 0 only) ----
  if (blockIdx.x != 0) return;
  for (int i = tid; i < KC * DD; i += NTHR)
    ((float*)cs)[i] = agload(&sums[i]) / agload(&denomf[i >> 7]);
  __syncthreads();
  const int k = tid;
  if (k < DD) {
    for (int i = 0; i < KC; ++i) {
      float aq = 0.f, av = 0.f;
      for (int m = 0; m < DD; ++m) {
        const float cm = cs[i][m];
        aq += cm * WQ[m * DD + k];
        av += cm * WV[m * DD + k];
      }
      q[i][k] = aq;
      vv[i][k] = av;
    }
  }
  __syncthreads();
  if (k < KC * KC) {
    const int i = k / KC, l = k % KC;
    float a2 = 0.f;
    for (int m = 0; m < DD; ++m) a2 += q[i][m] * vv[l][m];
    pr[i][l] = a2 / sqrtf((float)DD);
  }
  __syncthreads();
  if (k < KC) {
    float mx = pr[k][0];
    for (int l = 1; l < KC; ++l) mx = fmaxf(mx, pr[k][l]);
    float e[KC];
    float s = 0.f;
    for (int l = 0; l < KC; ++l) {
      e[l] = expf(pr[k][l] - mx);
      s += e[l];
    }
    for (int l = 0; l < KC; ++l) CA[k * KC + l] = e[l] / s;
  }
}

// ------------- edge histogram -------------
__global__ __launch_bounds__(256) void k_cnt(const int* __restrict__ e0,
                                             const int* __restrict__ e1,
                                             const unsigned char* __restrict__ cl8,
                                             int* __restrict__ cnt) {
  const int i = blockIdx.x * 256 + threadIdx.x;  // [0, NE/4)
  const int4 a = ((const int4*)e0)[i];
  const int4 b = ((const int4*)e1)[i];
  atomicAdd(&cnt[(size_t)a.x * KC + cl8[b.x]], 1);
  atomicAdd(&cnt[(size_t)a.y * KC + cl8[b.y]], 1);
  atomicAdd(&cnt[(size_t)a.z * KC + cl8[b.z]], 1);
  atomicAdd(&cnt[(size_t)a.w * KC + cl8[b.w]], 1);
}

// ------------- per-node denominator (row-max shift) -------------
__global__ __launch_bounds__(256) void k_tab2(
    const unsigned char* __restrict__ cl8, const int* __restrict__ cnt,
    const float* __restrict__ CA, float* __restrict__ den) {
  __shared__ float cas[KC * KC];
  __shared__ float rm[KC];
  if (threadIdx.x < KC * KC) cas[threadIdx.x] = CA[threadIdx.x];
  __syncthreads();
  if (threadIdx.x < KC) {
    float m = cas[threadIdx.x * KC];
    for (int l = 1; l < KC; ++l) m = fmaxf(m, cas[threadIdx.x * KC + l]);
    rm[threadIdx.x] = m;
  }
  __syncthreads();
  const int n = blockIdx.x * 256 + threadIdx.x;
  if (n >= NN) return;
  const int s = cl8[n];
  const float m = rm[s];
  float dsum = 0.f;
#pragma unroll
  for (int j = 0; j < KC; ++j) {
    const int cj = cnt[(size_t)n * KC + j];
    dsum += (float)cj * expf(cas[s * KC + j] - m);
  }
  den[n] = dsum;
}

// ------------- gather: out[e] = exp(ca - rm) / (den + eps) -------------
__global__ __launch_bounds__(256) void k_gather2(
    const int* __restrict__ e0, const int* __restrict__ e1,
    const unsigned char* __restrict__ cl8, const float* __restrict__ CA,
    const float* __restrict__ den, float* __restrict__ out) {
  __shared__ float cas[KC * KC];
  __shared__ float rm[KC];
  if (threadIdx.x < KC * KC) cas[threadIdx.x] = CA[threadIdx.x];
  __syncthreads();
  if (threadIdx.x < KC) {
    float m = cas[threadIdx.x * KC];
    for (int l = 1; l < KC; ++l) m = fmaxf(m, cas[threadIdx.x * KC + l]);
    rm[threadIdx.x] = m;
  }
  __syncthreads();
  const int i = blockIdx.x * 256 + threadIdx.x;  // [0, NE/4)
  const int4 a = ((const int4*)e0)[i];
  const int4 b = ((const int4*)e1)[i];
  float4 r;
  {
    const int s = cl8[a.x];
    r.x = expf(cas[s * KC + cl8[b.x]] - rm[s]) / (den[a.x] + 1e-16f);
  }
  {
    const int s = cl8[a.y];
    r.y = expf(cas[s * KC + cl8[b.y]] - rm[s]) / (den[a.y] + 1e-16f);
  }
  {
    const int s = cl8[a.z];
    r.z = expf(cas[s * KC + cl8[b.z]] - rm[s]) / (den[a.z] + 1e-16f);
  }
  {
    const int s = cl8[a.w];
    r.w = expf(cas[s * KC + cl8[b.w]] - rm[s]) / (den[a.w] + 1e-16f);
  }
  ((float4*)out)[i] = r;
}

// ---------------- launch ----------------
extern "C" void kernel_launch(void* const* d_in, const int* in_sizes, int n_in,
                              void* d_out, int out_size, void* d_ws,
                              size_t ws_size, hipStream_t stream) {
  const float* x = (const float*)d_in[0];
  const int* edge = (const int*)d_in[1];
  const float* WQ = (const float*)d_in[2];
  const float* WV = (const float*)d_in[3];
  float* out = (float*)d_out;
  const int* e0 = edge;
  const int* e1 = edge + NE;

  float* ws = (float*)d_ws;
  float* sums = ws;                                   // 1280
  float* denomf = ws + 1280;                          // 16 (pad)
  float* CA = ws + 1296;                              // 112 (pad)
  float* den = ws + 1408;                             // NN
  float* partial = den + NN;                          // NBK*KC*DD
  float* cntpart = partial + (size_t)NBK * KC * DD;   // NBK*KC
  int* cnt = (int*)(cntpart + NBK * KC);              // NN*KC ints
  unsigned char* cl8 = (unsigned char*)(cnt + (size_t)NN * KC);  // NN bytes
  int* bar = (int*)(cl8 + ((NN + 127) & ~127));       // barrier counter
  // total ~7.3 MB

  hipMemsetAsync(cnt, 0, (size_t)NN * KC * sizeof(int), stream);
  hipMemsetAsync(bar, 0, 64, stream);

  k_coop<<<NBK, NTHR, 0, stream>>>(x, WQ, WV, sums, denomf, partial, cntpart,
                                   cl8, CA, bar);
  k_cnt<<<NE / 4 / 256, 256, 0, stream>>>(e0, e1, cl8, cnt);
  k_tab2<<<(NN + 255) / 256, 256, 0, stream>>>(cl8, cnt, CA, den);
  k_gather2<<<NE / 4 / 256, 256, 0, stream>>>(e0, e1, cl8, CA, den, out);
}

// Round 5
// 1159.207 us; speedup vs baseline: 1.7088x; 1.7088x over previous
//
#include <hip/hip_runtime.h>

#define NN 100000
#define NE 3200000
#define DD 128
#define KC 10
#define NITER 10
#define NBLK 512   // k_iter blocks
#define RPB 200    // rows per block (512*200 = 102400 >= NN)

// ---------------- init: cnorm[j] = ||x_j||^2, j<KC ----------------
__global__ void k_init(const float* __restrict__ x, float* __restrict__ cnorm) {
  const int j = blockIdx.x, l = threadIdx.x;  // <<<KC, 64>>>
  const float2 v = ((const float2*)x)[j * 64 + l];
  float s = v.x * v.x + v.y * v.y;
#pragma unroll
  for (int m = 1; m < 64; m <<= 1) s += __shfl_xor(s, m);
  if (l == 0) cnorm[j] = s;
}

// ------------- fused assign (thread-per-row) + accumulate (half-wave-per-row)
__global__ __launch_bounds__(256) void k_iter(
    const float* __restrict__ x, const float* __restrict__ csrc,
    const float* __restrict__ cnorm, float* __restrict__ partial,
    float* __restrict__ cntpart, unsigned char* __restrict__ cl8, int last) {
  __shared__ float cs[KC][DD];
  __shared__ float cn[KC];
  __shared__ float wsum[4][KC][DD];
  __shared__ float wcnt[4][KC];
  __shared__ unsigned char bestl[RPB];
  const int tid = threadIdx.x;
  for (int i = tid; i < KC * DD; i += 256) ((float*)cs)[i] = csrc[i];
  if (tid < KC) cn[tid] = cnorm[tid];
  __syncthreads();

  const int n0 = blockIdx.x * RPB;

  // ---- pass 1: thread-per-row argmax( dot(x,c) - 0.5*|c|^2 ) ----
  if (tid < RPB && n0 + tid < NN) {
    const int n = n0 + tid;
    const float4* __restrict__ xr = (const float4*)(x + (size_t)n * DD);
    float d[KC];
#pragma unroll
    for (int j = 0; j < KC; ++j) d[j] = -0.5f * cn[j];
#pragma unroll 4
    for (int k4 = 0; k4 < DD / 4; ++k4) {
      const float4 xv = xr[k4];
#pragma unroll
      for (int j = 0; j < KC; ++j) {
        const float4 cv = *(const float4*)&cs[j][k4 * 4];
        d[j] += xv.x * cv.x + xv.y * cv.y + xv.z * cv.z + xv.w * cv.w;
      }
    }
    int best = 0;
    float bd = d[0];
#pragma unroll
    for (int j = 1; j < KC; ++j) {
      if (d[j] > bd) { bd = d[j]; best = j; }
    }
    bestl[tid] = (unsigned char)best;
    if (last) cl8[n] = (unsigned char)best;
  } else if (tid < RPB) {
    bestl[tid] = 255;
  }
  __syncthreads();

  // ---- pass 2: half-wave-per-row accumulate into register acc[j] ----
  const int w = tid >> 6, lane = tid & 63, half = lane >> 5, hl = lane & 31;
  float4 acc[KC];
  float cntacc[KC];
#pragma unroll
  for (int j = 0; j < KC; ++j) {
    acc[j] = float4{0.f, 0.f, 0.f, 0.f};
    cntacc[j] = 0.f;
  }
  const float4* __restrict__ x4 = (const float4*)x;
  const int p0 = w * (RPB / 8);  // RPB/2 pairs over 4 waves
  for (int p = p0; p < p0 + RPB / 8; ++p) {
    const int r = 2 * p + half;           // row within block
    const int row = n0 + r;
    const int best = bestl[r];            // LDS broadcast per half-wave
    float4 v = float4{0.f, 0.f, 0.f, 0.f};
    if (row < NN) v = x4[(size_t)row * (DD / 4) + hl];
#pragma unroll
    for (int j = 0; j < KC; ++j) {
      const float f = (best == j) ? 1.f : 0.f;
      acc[j].x += f * v.x;
      acc[j].y += f * v.y;
      acc[j].z += f * v.z;
      acc[j].w += f * v.w;
      cntacc[j] += (hl == 0) ? f : 0.f;
    }
  }
  // combine the two halves (lane ^ 32), flush half 0 into per-wave LDS
#pragma unroll
  for (int j = 0; j < KC; ++j) {
    acc[j].x += __shfl_xor(acc[j].x, 32);
    acc[j].y += __shfl_xor(acc[j].y, 32);
    acc[j].z += __shfl_xor(acc[j].z, 32);
    acc[j].w += __shfl_xor(acc[j].w, 32);
    cntacc[j] += __shfl_xor(cntacc[j], 32);
  }
  if (half == 0) {
#pragma unroll
    for (int j = 0; j < KC; ++j) *(float4*)&wsum[w][j][hl * 4] = acc[j];
    if (hl == 0) {
#pragma unroll
      for (int j = 0; j < KC; ++j) wcnt[w][j] = cntacc[j];
    }
  }
  __syncthreads();
  const float* wsf = (const float*)wsum;
  for (int i = tid; i < KC * DD; i += 256)
    partial[(size_t)blockIdx.x * (KC * DD) + i] =
        wsf[i] + wsf[KC * DD + i] + wsf[2 * KC * DD + i] + wsf[3 * KC * DD + i];
  if (tid < KC)
    cntpart[blockIdx.x * KC + tid] =
        wcnt[0][tid] + wcnt[1][tid] + wcnt[2][tid] + wcnt[3][tid];
}

// ------------- centroid update (deterministic reduce) -------------
__global__ __launch_bounds__(256) void k_update(
    const float* __restrict__ partial, const float* __restrict__ cntpart,
    float* __restrict__ c, float* __restrict__ cnorm) {
  const int j = blockIdx.x, tid = threadIdx.x;  // <<<KC, 256>>>
  __shared__ float red[256];
  __shared__ float dsh;
  float cf = 0.f;
  for (int b = tid; b < NBLK; b += 256) cf += cntpart[b * KC + j];
  red[tid] = cf;
  __syncthreads();
  for (int s = 128; s > 0; s >>= 1) {
    if (tid < s) red[tid] += red[tid + s];
    __syncthreads();
  }
  if (tid == 0) dsh = fmaxf(red[0], 1.f);
  __syncthreads();
  const float denom = dsh;
  __syncthreads();
  const int k = tid & 127, h = tid >> 7;
  float s0 = 0.f;
  for (int b = h * (NBLK / 2); b < (h + 1) * (NBLK / 2); ++b)
    s0 += partial[(size_t)b * (KC * DD) + j * DD + k];
  red[tid] = s0;
  __syncthreads();
  if (tid < DD) {
    const float cj = (red[tid] + red[tid + 128]) / denom;
    c[j * DD + tid] = cj;
    red[tid] = cj * cj;
  }
  __syncthreads();
  for (int s = 64; s > 0; s >>= 1) {
    if (tid < s) red[tid] += red[tid + s];
    __syncthreads();
  }
  if (tid == 0) cnorm[j] = red[0];
}

// ------------- centroid attention (10x10) -------------
__global__ __launch_bounds__(DD) void k_ca(const float* __restrict__ c,
                                           const float* __restrict__ WQ,
                                           const float* __restrict__ WV,
                                           float* __restrict__ CA) {
  __shared__ float cs[KC][DD], q[KC][DD], v[KC][DD], pr[KC][KC];
  const int k = threadIdx.x;  // <<<1, DD>>>
  for (int i = 0; i < KC; ++i) cs[i][k] = c[i * DD + k];
  __syncthreads();
  for (int i = 0; i < KC; ++i) {
    float aq = 0.f, av = 0.f;
    for (int m = 0; m < DD; ++m) {
      const float cm = cs[i][m];
      aq += cm * WQ[m * DD + k];
      av += cm * WV[m * DD + k];
    }
    q[i][k] = aq;
    v[i][k] = av;
  }
  __syncthreads();
  if (k < KC * KC) {
    const int i = k / KC, l = k % KC;
    float acc = 0.f;
    for (int m = 0; m < DD; ++m) acc += q[i][m] * v[l][m];
    pr[i][l] = acc / sqrtf((float)DD);
  }
  __syncthreads();
  if (k < KC) {
    float mx = pr[k][0];
    for (int l = 1; l < KC; ++l) mx = fmaxf(mx, pr[k][l]);
    float e[KC];
    float s = 0.f;
    for (int l = 0; l < KC; ++l) {
      e[l] = expf(pr[k][l] - mx);
      s += e[l];
    }
    for (int l = 0; l < KC; ++l) CA[k * KC + l] = e[l] / s;
  }
}

// ------------- edge histogram -------------
__global__ __launch_bounds__(256) void k_cnt(const int* __restrict__ e0,
                                             const int* __restrict__ e1,
                                             const unsigned char* __restrict__ cl8,
                                             int* __restrict__ cnt) {
  const int i = blockIdx.x * 256 + threadIdx.x;  // [0, NE/4)
  const int4 a = ((const int4*)e0)[i];
  const int4 b = ((const int4*)e1)[i];
  atomicAdd(&cnt[(size_t)a.x * KC + cl8[b.x]], 1);
  atomicAdd(&cnt[(size_t)a.y * KC + cl8[b.y]], 1);
  atomicAdd(&cnt[(size_t)a.z * KC + cl8[b.z]], 1);
  atomicAdd(&cnt[(size_t)a.w * KC + cl8[b.w]], 1);
}

// ------------- per-node denominator (row-max shift) -------------
__global__ __launch_bounds__(256) void k_tab2(
    const unsigned char* __restrict__ cl8, const int* __restrict__ cnt,
    const float* __restrict__ CA, float* __restrict__ den) {
  __shared__ float cas[KC * KC];
  __shared__ float rm[KC];
  if (threadIdx.x < KC * KC) cas[threadIdx.x] = CA[threadIdx.x];
  __syncthreads();
  if (threadIdx.x < KC) {
    float m = cas[threadIdx.x * KC];
    for (int l = 1; l < KC; ++l) m = fmaxf(m, cas[threadIdx.x * KC + l]);
    rm[threadIdx.x] = m;
  }
  __syncthreads();
  const int n = blockIdx.x * 256 + threadIdx.x;
  if (n >= NN) return;
  const int s = cl8[n];
  const float m = rm[s];
  float dsum = 0.f;
#pragma unroll
  for (int j = 0; j < KC; ++j) {
    const int cj = cnt[(size_t)n * KC + j];
    dsum += (float)cj * expf(cas[s * KC + j] - m);
  }
  den[n] = dsum;
}

// ------------- gather: out[e] = exp(ca - rm) / (den + eps) -------------
__global__ __launch_bounds__(256) void k_gather2(
    const int* __restrict__ e0, const int* __restrict__ e1,
    const unsigned char* __restrict__ cl8, const float* __restrict__ CA,
    const float* __restrict__ den, float* __restrict__ out) {
  __shared__ float cas[KC * KC];
  __shared__ float rm[KC];
  if (threadIdx.x < KC * KC) cas[threadIdx.x] = CA[threadIdx.x];
  __syncthreads();
  if (threadIdx.x < KC) {
    float m = cas[threadIdx.x * KC];
    for (int l = 1; l < KC; ++l) m = fmaxf(m, cas[threadIdx.x * KC + l]);
    rm[threadIdx.x] = m;
  }
  __syncthreads();
  const int i = blockIdx.x * 256 + threadIdx.x;  // [0, NE/4)
  const int4 a = ((const int4*)e0)[i];
  const int4 b = ((const int4*)e1)[i];
  float4 r;
  {
    const int s = cl8[a.x];
    r.x = expf(cas[s * KC + cl8[b.x]] - rm[s]) / (den[a.x] + 1e-16f);
  }
  {
    const int s = cl8[a.y];
    r.y = expf(cas[s * KC + cl8[b.y]] - rm[s]) / (den[a.y] + 1e-16f);
  }
  {
    const int s = cl8[a.z];
    r.z = expf(cas[s * KC + cl8[b.z]] - rm[s]) / (den[a.z] + 1e-16f);
  }
  {
    const int s = cl8[a.w];
    r.w = expf(cas[s * KC + cl8[b.w]] - rm[s]) / (den[a.w] + 1e-16f);
  }
  ((float4*)out)[i] = r;
}

// ---------------- launch ----------------
extern "C" void kernel_launch(void* const* d_in, const int* in_sizes, int n_in,
                              void* d_out, int out_size, void* d_ws,
                              size_t ws_size, hipStream_t stream) {
  const float* x = (const float*)d_in[0];
  const int* edge = (const int*)d_in[1];
  const float* WQ = (const float*)d_in[2];
  const float* WV = (const float*)d_in[3];
  float* out = (float*)d_out;
  const int* e0 = edge;
  const int* e1 = edge + NE;

  float* ws = (float*)d_ws;
  float* c = ws;                                     // 1280
  float* cnorm = ws + 1280;                          // 16 (pad)
  float* CA = ws + 1296;                             // 112 (pad)
  float* den = ws + 1408;                            // NN
  float* partial = den + NN;                         // NBLK*KC*DD = 655360
  float* cntpart = partial + (size_t)NBLK * KC * DD; // NBLK*KC = 5120
  int* cnt = (int*)(cntpart + NBLK * KC);            // NN*KC ints
  unsigned char* cl8 = (unsigned char*)(cnt + (size_t)NN * KC);  // NN bytes
  // total ~7.1 MB

  hipMemsetAsync(cnt, 0, (size_t)NN * KC * sizeof(int), stream);

  k_init<<<KC, 64, 0, stream>>>(x, cnorm);
  for (int it = 0; it < NITER; ++it) {
    const float* csrc = (it == 0) ? x : c;
    k_iter<<<NBLK, 256, 0, stream>>>(x, csrc, cnorm, partial, cntpart, cl8,
                                     it == NITER - 1);
    k_update<<<KC, 256, 0, stream>>>(partial, cntpart, c, cnorm);
  }
  k_ca<<<1, DD, 0, stream>>>(c, WQ, WV, CA);
  k_cnt<<<NE / 4 / 256, 256, 0, stream>>>(e0, e1, cl8, cnt);
  k_tab2<<<(NN + 255) / 256, 256, 0, stream>>>(cl8, cnt, CA, den);
  k_gather2<<<NE / 4 / 256, 256, 0, stream>>>(e0, e1, cl8, CA, den, out);
}

// Round 6
// 1022.397 us; speedup vs baseline: 1.9374x; 1.1338x over previous
//
#include <hip/hip_runtime.h>

#define NN 100000
#define NE 3200000
#define DD 128
#define KC 10
#define NITER 10
#define NBK 1024   // k_iter blocks = 4 per CU
#define NPAIR (NN / 2)

template <int CTRL, int RM>
__device__ __forceinline__ float dppadd(float v) {
  int t = __builtin_amdgcn_update_dpp(0, __builtin_bit_cast(int, v), CTRL, RM,
                                      0xF, true);
  return v + __builtin_bit_cast(float, t);
}

// After this: lane 31 holds sum of lanes 0..31, lane 63 holds sum of 32..63.
__device__ __forceinline__ float halfsum_tail(float v) {
  v = dppadd<0x111, 0xF>(v);  // row_shr:1
  v = dppadd<0x112, 0xF>(v);  // row_shr:2
  v = dppadd<0x114, 0xF>(v);  // row_shr:4
  v = dppadd<0x118, 0xF>(v);  // row_shr:8
  v = dppadd<0x142, 0xA>(v);  // row_bcast:15 into rows 1,3
  return v;
}
// broadcast lane 31 -> lanes 0..31 and lane 63 -> lanes 32..63
__device__ __forceinline__ int bcast31i(int v) {
  return __builtin_amdgcn_ds_swizzle(v, 0x3E0);
}

// ------------- fused assign + accumulate, half-wave per row -------------
__global__ __launch_bounds__(256, 4) void k_iter(
    const float* __restrict__ x, const float* __restrict__ csrc,
    float* __restrict__ partial, float* __restrict__ cntpart,
    unsigned char* __restrict__ cl8, int last) {
  __shared__ float cs[KC][DD];
  __shared__ float wsum[4][KC][DD];
  __shared__ float wcnt[4][KC];
  const int tid = threadIdx.x;
  for (int i = tid; i < KC * DD; i += 256) ((float*)cs)[i] = csrc[i];
  __syncthreads();
  const int w = tid >> 6, lane = tid & 63, half = lane >> 5, hl = lane & 31;

  // per-lane centroid fragment + bias = -0.5*|c_frag|^2
  float4 cfrag[KC];
  float bias[KC];
#pragma unroll
  for (int j = 0; j < KC; ++j) {
    const float4 c4 = *(const float4*)&cs[j][hl * 4];
    cfrag[j] = c4;
    bias[j] = -0.5f * (c4.x * c4.x + c4.y * c4.y + c4.z * c4.z + c4.w * c4.w);
  }

  float4 acc[KC];
  float cntacc[KC];
#pragma unroll
  for (int j = 0; j < KC; ++j) {
    acc[j] = float4{0.f, 0.f, 0.f, 0.f};
    cntacc[j] = 0.f;
  }

  const float4* __restrict__ x4 = (const float4*)x;
  // score = dot(x,c) - 0.5|c|^2 ; argmax == argmin dist (strict >, first wins)
  for (int p = blockIdx.x * 4 + w; p < NPAIR; p += NBK * 4) {
    const int row = 2 * p + half;
    const float4 v = x4[(size_t)row * (DD / 4) + hl];
    float d[KC];
#pragma unroll
    for (int j = 0; j < KC; ++j)
      d[j] = bias[j] + v.x * cfrag[j].x + v.y * cfrag[j].y + v.z * cfrag[j].z +
             v.w * cfrag[j].w;
#pragma unroll
    for (int j = 0; j < KC; ++j) d[j] = halfsum_tail(d[j]);
    int best = 0;  // meaningful in lanes 31/63 only
    float bd = d[0];
#pragma unroll
    for (int j = 1; j < KC; ++j) {
      if (d[j] > bd) { bd = d[j]; best = j; }
    }
    best = bcast31i(best);
    const float g = (hl == 0) ? 1.f : 0.f;
#pragma unroll
    for (int j = 0; j < KC; ++j) {
      const float f = (best == j) ? 1.f : 0.f;
      acc[j].x += f * v.x;
      acc[j].y += f * v.y;
      acc[j].z += f * v.z;
      acc[j].w += f * v.w;
      cntacc[j] += (best == j) ? g : 0.f;
    }
    if (last && hl == 0) cl8[row] = (unsigned char)best;
  }
  // combine the two halves (lane ^ 32), flush half 0 into per-wave LDS
#pragma unroll
  for (int j = 0; j < KC; ++j) {
    acc[j].x += __shfl_xor(acc[j].x, 32);
    acc[j].y += __shfl_xor(acc[j].y, 32);
    acc[j].z += __shfl_xor(acc[j].z, 32);
    acc[j].w += __shfl_xor(acc[j].w, 32);
    cntacc[j] += __shfl_xor(cntacc[j], 32);
  }
  if (half == 0) {
#pragma unroll
    for (int j = 0; j < KC; ++j) *(float4*)&wsum[w][j][hl * 4] = acc[j];
    if (hl == 0) {
#pragma unroll
      for (int j = 0; j < KC; ++j) wcnt[w][j] = cntacc[j];
    }
  }
  __syncthreads();
  const float* wsf = (const float*)wsum;
  for (int i = tid; i < KC * DD; i += 256)
    partial[(size_t)blockIdx.x * (KC * DD) + i] =
        wsf[i] + wsf[KC * DD + i] + wsf[2 * KC * DD + i] + wsf[3 * KC * DD + i];
  if (tid < KC)
    cntpart[blockIdx.x * KC + tid] =
        wcnt[0][tid] + wcnt[1][tid] + wcnt[2][tid] + wcnt[3][tid];
}

// ------------- centroid update: block = (j, quarter of columns) -------------
__global__ __launch_bounds__(256) void k_update(
    const float* __restrict__ partial, const float* __restrict__ cntpart,
    float* __restrict__ c) {
  const int j = blockIdx.x >> 2, q = blockIdx.x & 3;  // <<<KC*4, 256>>>
  const int tid = threadIdx.x;
  __shared__ float creds[256];
  __shared__ float red[8][32];
  float cf = 0.f;
  for (int b = tid; b < NBK; b += 256) cf += cntpart[b * KC + j];
  creds[tid] = cf;
  __syncthreads();
  for (int s = 128; s > 0; s >>= 1) {
    if (tid < s) creds[tid] += creds[tid + s];
    __syncthreads();
  }
  const float denom = fmaxf(creds[0], 1.f);
  const int col = q * 32 + (tid & 31);
  const int r0 = tid >> 5;  // 0..7
  float s0 = 0.f;
  for (int b = r0; b < NBK; b += 8)
    s0 += partial[(size_t)b * (KC * DD) + j * DD + col];
  red[r0][tid & 31] = s0;
  __syncthreads();
  if (tid < 32) {
    float t = 0.f;
#pragma unroll
    for (int r = 0; r < 8; ++r) t += red[r][tid];
    c[j * DD + q * 32 + tid] = t / denom;
  }
}

// ------------- centroid attention (10x10) -------------
__global__ __launch_bounds__(DD) void k_ca(const float* __restrict__ c,
                                           const float* __restrict__ WQ,
                                           const float* __restrict__ WV,
                                           float* __restrict__ CA) {
  __shared__ float cs[KC][DD], q[KC][DD], v[KC][DD], pr[KC][KC];
  const int k = threadIdx.x;  // <<<1, DD>>>
  for (int i = 0; i < KC; ++i) cs[i][k] = c[i * DD + k];
  __syncthreads();
  for (int i = 0; i < KC; ++i) {
    float aq = 0.f, av = 0.f;
    for (int m = 0; m < DD; ++m) {
      const float cm = cs[i][m];
      aq += cm * WQ[m * DD + k];
      av += cm * WV[m * DD + k];
    }
    q[i][k] = aq;
    v[i][k] = av;
  }
  __syncthreads();
  if (k < KC * KC) {
    const int i = k / KC, l = k % KC;
    float acc = 0.f;
    for (int m = 0; m < DD; ++m) acc += q[i][m] * v[l][m];
    pr[i][l] = acc / sqrtf((float)DD);
  }
  __syncthreads();
  if (k < KC) {
    float mx = pr[k][0];
    for (int l = 1; l < KC; ++l) mx = fmaxf(mx, pr[k][l]);
    float e[KC];
    float s = 0.f;
    for (int l = 0; l < KC; ++l) {
      e[l] = expf(pr[k][l] - mx);
      s += e[l];
    }
    for (int l = 0; l < KC; ++l) CA[k * KC + l] = e[l] / s;
  }
}

// ------------- edge histogram -------------
__global__ __launch_bounds__(256) void k_cnt(const int* __restrict__ e0,
                                             const int* __restrict__ e1,
                                             const unsigned char* __restrict__ cl8,
                                             int* __restrict__ cnt) {
  const int i = blockIdx.x * 256 + threadIdx.x;  // [0, NE/4)
  const int4 a = ((const int4*)e0)[i];
  const int4 b = ((const int4*)e1)[i];
  atomicAdd(&cnt[(size_t)a.x * KC + cl8[b.x]], 1);
  atomicAdd(&cnt[(size_t)a.y * KC + cl8[b.y]], 1);
  atomicAdd(&cnt[(size_t)a.z * KC + cl8[b.z]], 1);
  atomicAdd(&cnt[(size_t)a.w * KC + cl8[b.w]], 1);
}

// ------------- per-node denominator (row-max shift) -------------
__global__ __launch_bounds__(256) void k_tab2(
    const unsigned char* __restrict__ cl8, const int* __restrict__ cnt,
    const float* __restrict__ CA, float* __restrict__ den) {
  __shared__ float cas[KC * KC];
  __shared__ float rm[KC];
  if (threadIdx.x < KC * KC) cas[threadIdx.x] = CA[threadIdx.x];
  __syncthreads();
  if (threadIdx.x < KC) {
    float m = cas[threadIdx.x * KC];
    for (int l = 1; l < KC; ++l) m = fmaxf(m, cas[threadIdx.x * KC + l]);
    rm[threadIdx.x] = m;
  }
  __syncthreads();
  const int n = blockIdx.x * 256 + threadIdx.x;
  if (n >= NN) return;
  const int s = cl8[n];
  const float m = rm[s];
  float dsum = 0.f;
#pragma unroll
  for (int j = 0; j < KC; ++j) {
    const int cj = cnt[(size_t)n * KC + j];
    dsum += (float)cj * expf(cas[s * KC + j] - m);
  }
  den[n] = dsum;
}

// ------------- gather: out[e] = exp(ca - rm) / (den + eps) -------------
__global__ __launch_bounds__(256) void k_gather2(
    const int* __restrict__ e0, const int* __restrict__ e1,
    const unsigned char* __restrict__ cl8, const float* __restrict__ CA,
    const float* __restrict__ den, float* __restrict__ out) {
  __shared__ float cas[KC * KC];
  __shared__ float rm[KC];
  if (threadIdx.x < KC * KC) cas[threadIdx.x] = CA[threadIdx.x];
  __syncthreads();
  if (threadIdx.x < KC) {
    float m = cas[threadIdx.x * KC];
    for (int l = 1; l < KC; ++l) m = fmaxf(m, cas[threadIdx.x * KC + l]);
    rm[threadIdx.x] = m;
  }
  __syncthreads();
  const int i = blockIdx.x * 256 + threadIdx.x;  // [0, NE/4)
  const int4 a = ((const int4*)e0)[i];
  const int4 b = ((const int4*)e1)[i];
  float4 r;
  {
    const int s = cl8[a.x];
    r.x = expf(cas[s * KC + cl8[b.x]] - rm[s]) / (den[a.x] + 1e-16f);
  }
  {
    const int s = cl8[a.y];
    r.y = expf(cas[s * KC + cl8[b.y]] - rm[s]) / (den[a.y] + 1e-16f);
  }
  {
    const int s = cl8[a.z];
    r.z = expf(cas[s * KC + cl8[b.z]] - rm[s]) / (den[a.z] + 1e-16f);
  }
  {
    const int s = cl8[a.w];
    r.w = expf(cas[s * KC + cl8[b.w]] - rm[s]) / (den[a.w] + 1e-16f);
  }
  ((float4*)out)[i] = r;
}

// ---------------- launch ----------------
extern "C" void kernel_launch(void* const* d_in, const int* in_sizes, int n_in,
                              void* d_out, int out_size, void* d_ws,
                              size_t ws_size, hipStream_t stream) {
  const float* x = (const float*)d_in[0];
  const int* edge = (const int*)d_in[1];
  const float* WQ = (const float*)d_in[2];
  const float* WV = (const float*)d_in[3];
  float* out = (float*)d_out;
  const int* e0 = edge;
  const int* e1 = edge + NE;

  float* ws = (float*)d_ws;
  float* c = ws;                                     // 1280
  float* CA = ws + 1280;                             // 112 (pad)
  float* den = ws + 1392;                            // NN
  float* partial = den + NN;                         // NBK*KC*DD = 1,310,720
  float* cntpart = partial + (size_t)NBK * KC * DD;  // NBK*KC = 10240
  int* cnt = (int*)(cntpart + NBK * KC);             // NN*KC ints
  unsigned char* cl8 = (unsigned char*)(cnt + (size_t)NN * KC);  // NN bytes
  // total ~9.8 MB

  hipMemsetAsync(cnt, 0, (size_t)NN * KC * sizeof(int), stream);

  for (int it = 0; it < NITER; ++it) {
    const float* csrc = (it == 0) ? x : c;
    k_iter<<<NBK, 256, 0, stream>>>(x, csrc, partial, cntpart, cl8,
                                    it == NITER - 1);
    k_update<<<KC * 4, 256, 0, stream>>>(partial, cntpart, c);
  }
  k_ca<<<1, DD, 0, stream>>>(c, WQ, WV, CA);
  k_cnt<<<NE / 4 / 256, 256, 0, stream>>>(e0, e1, cl8, cnt);
  k_tab2<<<(NN + 255) / 256, 256, 0, stream>>>(cl8, cnt, CA, den);
  k_gather2<<<NE / 4 / 256, 256, 0, stream>>>(e0, e1, cl8, CA, den, out);
}